// Round 6
// baseline (55.508 us; speedup 1.0000x reference)
//
#include <hip/hip_runtime.h>
#include <math.h>

#define DIM 128

// native clang vector types — required by __builtin_nontemporal_load / packed stores
typedef float vfloat4 __attribute__((ext_vector_type(4)));
typedef int   vint4   __attribute__((ext_vector_type(4)));

__device__ __forceinline__ float reduce16(float v) {
    // butterfly reduce within each 16-lane group of the wave64 (result in all lanes)
    v += __shfl_xor(v, 1);
    v += __shfl_xor(v, 2);
    v += __shfl_xor(v, 4);
    v += __shfl_xor(v, 8);
    return v;
}

__device__ __forceinline__ float dp4(vfloat4 a, vfloat4 b) {
    return a.x * b.x + a.y * b.y + a.z * b.z + a.w * b.w;
}

__device__ __forceinline__ vfloat4 ntload(const float* p) {
    return __builtin_nontemporal_load(reinterpret_cast<const vfloat4*>(p));
}

__device__ __forceinline__ float sigmoidf(float x) {
    return 1.0f / (1.0f + __expf(-x));
}

// Kernel A: block-partitioned so the 27.6MB node read overlaps the 256MB edge stream.
//  blocks [0, node_blocks):       pk[n] = h[n]·Wk, pi[n] = h[n]·Wi
//  blocks [node_blocks, gridDim): s_e[edge] = e[edge]·We   (pure stream, no gathers)
// 16 lanes per row; lane l covers floats [4l,4l+4) and [64+4l,64+4l+4); 4 rows/iter.
__global__ __launch_bounds__(256) void fused_A(
        const float* __restrict__ h,
        const float* __restrict__ e,
        const float* __restrict__ W,
        float* __restrict__ pk,
        float* __restrict__ pi,
        float* __restrict__ s_e,
        int n_nodes,
        int n_edges,
        int node_blocks) {
    const int l = threadIdx.x & 15;

    if ((int)blockIdx.x < node_blocks) {
        // ---- node projection part ----
        const int group0 = ((blockIdx.x << 8) + threadIdx.x) >> 4;
        const int ngroups = node_blocks << 4;  // node_blocks*256/16

        const vfloat4 wk0 = *reinterpret_cast<const vfloat4*>(W + 4 * l);
        const vfloat4 wk1 = *reinterpret_cast<const vfloat4*>(W + 64 + 4 * l);
        const vfloat4 wi0 = *reinterpret_cast<const vfloat4*>(W + DIM + 4 * l);
        const vfloat4 wi1 = *reinterpret_cast<const vfloat4*>(W + DIM + 64 + 4 * l);

        const int n_full = n_nodes & ~3;

        for (int base = 4 * group0; base < n_full; base += 4 * ngroups) {
            const float* hp = h + (size_t)base * DIM;
            vfloat4 a0[4], a1[4];
#pragma unroll
            for (int j = 0; j < 4; ++j) {
                a0[j] = ntload(hp + (size_t)j * DIM + 4 * l);
                a1[j] = ntload(hp + (size_t)j * DIM + 64 + 4 * l);
            }
            float sk[4], si[4];
#pragma unroll
            for (int j = 0; j < 4; ++j) {
                sk[j] = reduce16(dp4(a0[j], wk0) + dp4(a1[j], wk1));
                si[j] = reduce16(dp4(a0[j], wi0) + dp4(a1[j], wi1));
            }
            if (l == 0) {
                vfloat4 vk; vk.x = sk[0]; vk.y = sk[1]; vk.z = sk[2]; vk.w = sk[3];
                vfloat4 vi; vi.x = si[0]; vi.y = si[1]; vi.z = si[2]; vi.w = si[3];
                *reinterpret_cast<vfloat4*>(pk + base) = vk;
                *reinterpret_cast<vfloat4*>(pi + base) = vi;
            }
        }
        for (int node = n_full + group0; node < n_nodes; node += ngroups) {
            const float* hp = h + (size_t)node * DIM;
            const vfloat4 a0 = ntload(hp + 4 * l);
            const vfloat4 a1 = ntload(hp + 64 + 4 * l);
            float sk = reduce16(dp4(a0, wk0) + dp4(a1, wk1));
            float si = reduce16(dp4(a0, wi0) + dp4(a1, wi1));
            if (l == 0) { pk[node] = sk; pi[node] = si; }
        }
    } else {
        // ---- edge dot-product part (pure streaming) ----
        const int bid2 = (int)blockIdx.x - node_blocks;
        const int group0 = ((bid2 << 8) + threadIdx.x) >> 4;
        const int ngroups = ((int)gridDim.x - node_blocks) << 4;

        const vfloat4 we0 = *reinterpret_cast<const vfloat4*>(W + 2 * DIM + 4 * l);
        const vfloat4 we1 = *reinterpret_cast<const vfloat4*>(W + 2 * DIM + 64 + 4 * l);

        const int n_full = n_edges & ~3;

        for (int base = 4 * group0; base < n_full; base += 4 * ngroups) {
            const float* ep = e + (size_t)base * DIM;
            vfloat4 a0[4], a1[4];
#pragma unroll
            for (int j = 0; j < 4; ++j) {
                a0[j] = ntload(ep + (size_t)j * DIM + 4 * l);
                a1[j] = ntload(ep + (size_t)j * DIM + 64 + 4 * l);
            }
            float s[4];
#pragma unroll
            for (int j = 0; j < 4; ++j)
                s[j] = reduce16(dp4(a0[j], we0) + dp4(a1[j], we1));

            if (l == 0) {
                vfloat4 o; o.x = s[0]; o.y = s[1]; o.z = s[2]; o.w = s[3];
                *reinterpret_cast<vfloat4*>(s_e + base) = o;
            }
        }
        for (int edge = n_full + group0; edge < n_edges; edge += ngroups) {
            const float* ep = e + (size_t)edge * DIM;
            const vfloat4 a0 = ntload(ep + 4 * l);
            const vfloat4 a1 = ntload(ep + 64 + 4 * l);
            float s = reduce16(dp4(a0, we0) + dp4(a1, we1));
            if (l == 0) s_e[edge] = s;
        }
    }
}

// Kernel B: out[edge] = sigmoid(s_e[edge] + pk[src] + pi[dst] + b). 4 edges/thread.
__global__ __launch_bounds__(256) void finish_kernel(
        const int* __restrict__ src,
        const int* __restrict__ dst,
        const float* __restrict__ b,
        const float* __restrict__ pk,
        const float* __restrict__ pi,
        const float* __restrict__ s_e,
        float* __restrict__ out,
        int n_edges) {
    const int tid = blockIdx.x * blockDim.x + threadIdx.x;
    const int nthreads = gridDim.x * blockDim.x;
    const int n_full = n_edges & ~3;
    const float b0 = b[0];

    for (int base = 4 * tid; base < n_full; base += 4 * nthreads) {
        const vint4 s4 = *reinterpret_cast<const vint4*>(src + base);
        const vint4 d4 = *reinterpret_cast<const vint4*>(dst + base);
        const vfloat4 se = *reinterpret_cast<const vfloat4*>(s_e + base);
        const float pk0 = pk[s4.x], pk1 = pk[s4.y], pk2 = pk[s4.z], pk3 = pk[s4.w];
        const float pi0 = pi[d4.x], pi1 = pi[d4.y], pi2 = pi[d4.z], pi3 = pi[d4.w];
        vfloat4 o;
        o.x = sigmoidf(se.x + pk0 + pi0 + b0);
        o.y = sigmoidf(se.y + pk1 + pi1 + b0);
        o.z = sigmoidf(se.z + pk2 + pi2 + b0);
        o.w = sigmoidf(se.w + pk3 + pi3 + b0);
        *reinterpret_cast<vfloat4*>(out + base) = o;
    }
    for (int edge = n_full + tid; edge < n_edges; edge += nthreads) {
        out[edge] = sigmoidf(s_e[edge] + pk[src[edge]] + pi[dst[edge]] + b0);
    }
}

// Mid fallback (ws fits pk/pi only): R5's two-kernel path.
__global__ __launch_bounds__(256) void node_proj_kernel(
        const float* __restrict__ h,
        const float* __restrict__ W,
        float* __restrict__ pk,
        float* __restrict__ pi,
        int n_nodes) {
    const int l = threadIdx.x & 15;
    const int group0 = (blockIdx.x * blockDim.x + threadIdx.x) >> 4;
    const int ngroups = (gridDim.x * blockDim.x) >> 4;

    const vfloat4 wk0 = *reinterpret_cast<const vfloat4*>(W + 4 * l);
    const vfloat4 wk1 = *reinterpret_cast<const vfloat4*>(W + 64 + 4 * l);
    const vfloat4 wi0 = *reinterpret_cast<const vfloat4*>(W + DIM + 4 * l);
    const vfloat4 wi1 = *reinterpret_cast<const vfloat4*>(W + DIM + 64 + 4 * l);

    for (int node = group0; node < n_nodes; node += ngroups) {
        const float* hp = h + (size_t)node * DIM;
        const vfloat4 a0 = ntload(hp + 4 * l);
        const vfloat4 a1 = ntload(hp + 64 + 4 * l);
        float sk = reduce16(dp4(a0, wk0) + dp4(a1, wk1));
        float si = reduce16(dp4(a0, wi0) + dp4(a1, wi1));
        if (l == 0) { pk[node] = sk; pi[node] = si; }
    }
}

__global__ __launch_bounds__(256) void edge_kernel(
        const float* __restrict__ e,
        const int* __restrict__ src,
        const int* __restrict__ dst,
        const float* __restrict__ W,
        const float* __restrict__ b,
        const float* __restrict__ pk,
        const float* __restrict__ pi,
        float* __restrict__ out,
        int n_edges) {
    const int l = threadIdx.x & 15;
    const int group0 = (blockIdx.x * blockDim.x + threadIdx.x) >> 4;
    const int ngroups = (gridDim.x * blockDim.x) >> 4;

    const vfloat4 we0 = *reinterpret_cast<const vfloat4*>(W + 2 * DIM + 4 * l);
    const vfloat4 we1 = *reinterpret_cast<const vfloat4*>(W + 2 * DIM + 64 + 4 * l);
    const float b0 = b[0];

    for (int edge = group0; edge < n_edges; edge += ngroups) {
        const int s_idx = src[edge];
        const int d_idx = dst[edge];
        const float pkv = pk[s_idx];
        const float piv = pi[d_idx];
        const float* ep = e + (size_t)edge * DIM;
        const vfloat4 a0 = ntload(ep + 4 * l);
        const vfloat4 a1 = ntload(ep + 64 + 4 * l);
        float s = reduce16(dp4(a0, we0) + dp4(a1, we1));
        if (l == 0) {
            out[edge] = sigmoidf(s + pkv + piv + b0);
        }
    }
}

// Last-resort fallback: fully fused, gathers h rows per edge.
__global__ void edge_fused_kernel(const float* __restrict__ h,
                                  const float* __restrict__ e,
                                  const int* __restrict__ src,
                                  const int* __restrict__ dst,
                                  const float* __restrict__ W,
                                  const float* __restrict__ b,
                                  float* __restrict__ out,
                                  int n_edges) {
    int tid  = blockIdx.x * blockDim.x + threadIdx.x;
    int edge = tid >> 5;
    int l    = tid & 31;
    if (edge >= n_edges) return;

    int s_idx = src[edge];
    int d_idx = dst[edge];

    const float4 hk = *reinterpret_cast<const float4*>(h + (size_t)s_idx * DIM + 4 * l);
    const float4 hi = *reinterpret_cast<const float4*>(h + (size_t)d_idx * DIM + 4 * l);
    const float4 ev = *reinterpret_cast<const float4*>(e + (size_t)edge * DIM + 4 * l);
    const float4 wk = *reinterpret_cast<const float4*>(W + 4 * l);
    const float4 wi = *reinterpret_cast<const float4*>(W + DIM + 4 * l);
    const float4 we = *reinterpret_cast<const float4*>(W + 2 * DIM + 4 * l);

    float s = hk.x * wk.x + hk.y * wk.y + hk.z * wk.z + hk.w * wk.w
            + hi.x * wi.x + hi.y * wi.y + hi.z * wi.z + hi.w * wi.w
            + ev.x * we.x + ev.y * we.y + ev.z * we.z + ev.w * we.w;
    s += __shfl_xor(s, 1);
    s += __shfl_xor(s, 2);
    s += __shfl_xor(s, 4);
    s += __shfl_xor(s, 8);
    s += __shfl_xor(s, 16);

    if (l == 0) {
        float logit = s + b[0];
        out[edge] = 1.0f / (1.0f + expf(-logit));
    }
}

extern "C" void kernel_launch(void* const* d_in, const int* in_sizes, int n_in,
                              void* d_out, int out_size, void* d_ws, size_t ws_size,
                              hipStream_t stream) {
    const float* h   = (const float*)d_in[0];
    const float* e   = (const float*)d_in[1];
    const int*   src = (const int*)d_in[2];
    const int*   dst = (const int*)d_in[3];
    const float* W   = (const float*)d_in[4];
    const float* b   = (const float*)d_in[5];
    float* out = (float*)d_out;

    const int n_nodes = in_sizes[0] / DIM;
    const int n_edges = in_sizes[2];

    const int n_nodes_pad = (n_nodes + 3) & ~3;  // keep s_e 16B-aligned
    const size_t ws_full = ((size_t)2 * n_nodes_pad + (size_t)n_edges) * sizeof(float);
    const size_t ws_mid  = (size_t)2 * n_nodes_pad * sizeof(float);

    if (ws_size >= ws_full) {
        float* pk  = (float*)d_ws;
        float* pi  = pk + n_nodes_pad;
        float* s_e = pi + n_nodes_pad;

        // Kernel A: node blocks sized by traffic share (~27.6MB of ~283MB ≈ 10%)
        const int grid_a = 2048;
        const int node_blocks = 200;
        fused_A<<<grid_a, 256, 0, stream>>>(h, e, W, pk, pi, s_e,
                                            n_nodes, n_edges, node_blocks);

        // Kernel B: 4 edges per thread
        long threads_b = ((long)n_edges + 3) / 4;
        int grid_b = (int)((threads_b + 255) / 256);
        if (grid_b > 2048) grid_b = 2048;
        if (grid_b < 1) grid_b = 1;
        finish_kernel<<<grid_b, 256, 0, stream>>>(src, dst, b, pk, pi, s_e, out, n_edges);
    } else if (ws_size >= ws_mid) {
        float* pk = (float*)d_ws;
        float* pi = pk + n_nodes_pad;

        {
            const int block = 256;
            long total = (long)n_nodes * 16;
            int grid = (int)((total + block - 1) / block);
            if (grid > 2048) grid = 2048;
            node_proj_kernel<<<grid, block, 0, stream>>>(h, W, pk, pi, n_nodes);
        }
        {
            const int block = 256;
            long total = (long)n_edges * 16;
            int grid = (int)((total + block - 1) / block);
            if (grid > 2048) grid = 2048;
            edge_kernel<<<grid, block, 0, stream>>>(e, src, dst, W, b, pk, pi, out, n_edges);
        }
    } else {
        int total = n_edges * 32;
        int block = 256;
        int grid  = (total + block - 1) / block;
        edge_fused_kernel<<<grid, block, 0, stream>>>(h, e, src, dst, W, b, out, n_edges);
    }
}